// Round 9
// baseline (512.913 us; speedup 1.0000x reference)
//
#include <hip/hip_runtime.h>
#include <cstdint>
#include <cstddef>

#define DEVFN __device__ __forceinline__
#define SCHEDB  __builtin_amdgcn_sched_barrier(0)
#define BARRIER __builtin_amdgcn_s_barrier()
#define LGKM0   asm volatile("s_waitcnt lgkmcnt(0)" ::: "memory")
#define WAITV(n) asm volatile("s_waitcnt vmcnt(" #n ")" ::: "memory")

typedef __attribute__((ext_vector_type(8))) __bf16 bf16x8;
typedef __attribute__((ext_vector_type(4))) float f32x4;

static constexpr int DM = 1024;
static constexpr int NH = 16;
static constexpr int HD = 64;
static constexpr int BATCH = 512;
static constexpr int SEQ = 64;
static constexpr int MROWS = BATCH * SEQ;   // 32768
static constexpr int KDIM = DM;             // 1024
static constexpr int NT = KDIM / 64;        // 16 k-tiles

DEVFN unsigned short f2bf(float f) {
  unsigned u = __builtin_bit_cast(unsigned, f);
  u += 0x7fffu + ((u >> 16) & 1u);   // RNE
  return (unsigned short)(u >> 16);
}

DEVFN void gload_lds16(const void* g, void* l) {
  __builtin_amdgcn_global_load_lds(
      (__attribute__((address_space(1))) const void*)g,
      (__attribute__((address_space(3))) void*)l, 16, 0, 0);
}

DEVFN unsigned ldsaddr(const void* p) {
  // AS3 pointers are 32-bit LDS byte offsets
  return (unsigned)(uintptr_t)(__attribute__((address_space(3))) const void*)p;
}

DEVFN bf16x8 ds128(unsigned off) {
  // opaque to alias analysis: compiler cannot order this vs gload_lds DMA;
  // WE order it via the vmcnt ledger + LGKM0 + SCHEDB (rule 18).
  bf16x8 r;
  asm volatile("ds_read_b128 %0, %1" : "=v"(r) : "v"(off));
  return r;
}

// ------- one-shot fp32 -> bf16 convert of x + Wq|Wk|Wv|Wo into xb|wb -------
__global__ void convert_all_kernel(const float* __restrict__ x,
                                   const float* __restrict__ w0,
                                   const float* __restrict__ w1,
                                   const float* __restrict__ w2,
                                   const float* __restrict__ w3,
                                   unsigned short* __restrict__ dst) {
  const size_t NX = (size_t)MROWS * DM;
  const size_t NTOT = NX + 4ull * DM * DM;
  size_t i = ((size_t)blockIdx.x * blockDim.x + threadIdx.x) * 4;
  const size_t stride = (size_t)gridDim.x * blockDim.x * 4;
  for (; i < NTOT; i += stride) {
    const float* s;
    size_t off;
    if (i < NX) { s = x; off = i; }
    else {
      size_t j = i - NX;
      const int seg = (int)(j >> 20);
      off = j & ((1u << 20) - 1);
      s = (seg == 0) ? w0 : (seg == 1) ? w1 : (seg == 2) ? w2 : w3;
    }
    float4 f = *reinterpret_cast<const float4*>(s + off);
    ushort4 o;
    o.x = f2bf(f.x); o.y = f2bf(f.y); o.z = f2bf(f.z); o.w = f2bf(f.w);
    *reinterpret_cast<ushort4*>(dst + i) = o;
  }
}

// ---------------- RoPE cos/sin table: [SEQ][512] float2 ---------------------
__global__ void rope_table_kernel(float2* __restrict__ tab) {
  int idx = blockIdx.x * blockDim.x + threadIdx.x;
  if (idx >= SEQ * 512) return;
  int s = idx >> 9, i = idx & 511;
  float inv_freq = exp2f(-(float)i * (13.287712379549449f / 512.0f));
  float ang = (float)s * inv_freq;
  tab[idx] = make_float2(cosf(ang), sinf(ang));
}

// ======= 256x256 GEMM, BK=64, 8 waves, faithful 8-phase counted-vmcnt ======
// C[M][N] = A[M][K]*B[N][K]^T. Staging unit = half-tile (256 rows x 32 k =
// 16KB, 2 gloads/wave). LDS [2 buf][2 kh][256*32] per operand = 128 KiB.
// Phase (kh,nh): asm ds_read subtile -> stage 1 half-tile -> barrier ->
// lgkmcnt(0) -> setprio(1) 16 MFMA setprio(0) -> barrier.
// Stage rotation (tile t): P1->B.kh1(t+1), P2->A.kh0(t+2), P3->B.kh0(t+2),
// P4->A.kh1(t+2). vmcnt(6) at P4 only: ledger-verified -- every half is
// guaranteed landed >=3 phases before first read; every stage target's last
// reader finished >=1 barrier before the stage issues (WAR-safe).
// Prologue: 4 halves, vmcnt(4), +3 halves, vmcnt(6) (template-exact).
template <int MODE>
__global__ __launch_bounds__(512, 1)
void gemm8p_kernel(const unsigned short* __restrict__ A,
                   const unsigned short* __restrict__ Bw,
                   const float* __restrict__ bias0,
                   const float* __restrict__ bias1,
                   const float* __restrict__ bias2,
                   const float2* __restrict__ rope,
                   unsigned short* __restrict__ qb,
                   unsigned short* __restrict__ kb,
                   unsigned short* __restrict__ vb,
                   float* __restrict__ outf,
                   int Ntiles) {
  __shared__ __align__(16) unsigned short sA[2][2][8192];  // 64 KB
  __shared__ __align__(16) unsigned short sB[2][2][8192];  // 64 KB

  const int cpx = gridDim.x >> 3;
  const int bid = (blockIdx.x & 7) * cpx + (blockIdx.x >> 3);
  const int bm = bid / Ntiles, bn = bid % Ntiles;
  const int m0 = bm * 256, n0 = bn * 256;

  const int tid = threadIdx.x, w = tid >> 6, lane = tid & 63;
  const int wr = w >> 2, wc = w & 3;   // 2M x 4N waves; 128x64 out per wave

  // staging: lane -> row w*16+(lane>>2) (+j*128), swizzled granule of 32-k half
  const int sr = w * 16 + (lane >> 2);
  const int sg = ((lane & 3) ^ ((lane >> 2) & 3)) * 8;
  const unsigned short* gA = A + ((size_t)m0 + sr) * KDIM + sg;
  const unsigned short* gB = Bw + ((size_t)n0 + sr) * KDIM + sg;
  const int ldst = w * 512;   // ushort offset of wave's 1KB slice in a unit

  auto STGA = [&](int buf, int kh, int tk) {
    const unsigned short* src = gA + tk * 64 + kh * 32;
    gload_lds16(src, &sA[buf][kh][ldst]);
    gload_lds16(src + (size_t)128 * KDIM, &sA[buf][kh][ldst + 4096]);
  };
  auto STGB = [&](int buf, int kh, int tk) {
    const unsigned short* src = gB + tk * 64 + kh * 32;
    gload_lds16(src, &sB[buf][kh][ldst]);
    gload_lds16(src + (size_t)128 * KDIM, &sB[buf][kh][ldst + 4096]);
  };

  // read offsets (bytes within a unit); granule XOR matches write swizzle
  const unsigned gq = ((unsigned)((lane >> 4) ^ (lane & 3))) * 16;
  const unsigned aoff = (unsigned)(wr * 128 + (lane & 15)) * 64 + gq;
  const unsigned boff = (unsigned)(wc * 64 + (lane & 15)) * 64 + gq;

  f32x4 acc[8][4] = {};

  // prologue: tile0 (4 halves), vmcnt(4), tile1 minus B.kh1 (3 halves), vmcnt(6)
  STGA(0, 0, 0); STGB(0, 0, 0); STGA(0, 1, 0); STGB(0, 1, 0);
  WAITV(4);
  STGA(1, 0, 1); STGB(1, 0, 1); STGA(1, 1, 1);
  WAITV(6);   // all of tile0 landed; 3 halves in flight
  SCHEDB; BARRIER;

#pragma unroll 1
  for (int t = 0; t < NT; ++t) {
    const int c = t & 1;
    const unsigned uA0 = ldsaddr(&sA[c][0][0]);
    const unsigned uA1 = ldsaddr(&sA[c][1][0]);
    const unsigned uB0 = ldsaddr(&sB[c][0][0]);
    const unsigned uB1 = ldsaddr(&sB[c][1][0]);
    bf16x8 a[8], b0, b1;

    // ---- P1: kh0, nh0 ----
#pragma unroll
    for (int mi = 0; mi < 8; ++mi) a[mi] = ds128(uA0 + aoff + mi * 1024);
    b0 = ds128(uB0 + boff);
    b1 = ds128(uB0 + boff + 1024);
    if (t + 1 < NT) STGB(c ^ 1, 1, t + 1);
    SCHEDB; BARRIER; LGKM0; SCHEDB;
    __builtin_amdgcn_s_setprio(1);
#pragma unroll
    for (int mi = 0; mi < 8; ++mi) {
      acc[mi][0] = __builtin_amdgcn_mfma_f32_16x16x32_bf16(a[mi], b0, acc[mi][0], 0, 0, 0);
      acc[mi][1] = __builtin_amdgcn_mfma_f32_16x16x32_bf16(a[mi], b1, acc[mi][1], 0, 0, 0);
    }
    __builtin_amdgcn_s_setprio(0);
    SCHEDB; BARRIER;

    // ---- P2: kh0, nh1 (a-frags held in regs) ----
    b0 = ds128(uB0 + boff + 2048);
    b1 = ds128(uB0 + boff + 3072);
    if (t + 2 < NT) STGA(c, 0, t + 2);
    SCHEDB; BARRIER; LGKM0; SCHEDB;
    __builtin_amdgcn_s_setprio(1);
#pragma unroll
    for (int mi = 0; mi < 8; ++mi) {
      acc[mi][2] = __builtin_amdgcn_mfma_f32_16x16x32_bf16(a[mi], b0, acc[mi][2], 0, 0, 0);
      acc[mi][3] = __builtin_amdgcn_mfma_f32_16x16x32_bf16(a[mi], b1, acc[mi][3], 0, 0, 0);
    }
    __builtin_amdgcn_s_setprio(0);
    SCHEDB; BARRIER;

    // ---- P3: kh1, nh0 ----
#pragma unroll
    for (int mi = 0; mi < 8; ++mi) a[mi] = ds128(uA1 + aoff + mi * 1024);
    b0 = ds128(uB1 + boff);
    b1 = ds128(uB1 + boff + 1024);
    if (t + 2 < NT) STGB(c, 0, t + 2);
    SCHEDB; BARRIER; LGKM0; SCHEDB;
    __builtin_amdgcn_s_setprio(1);
#pragma unroll
    for (int mi = 0; mi < 8; ++mi) {
      acc[mi][0] = __builtin_amdgcn_mfma_f32_16x16x32_bf16(a[mi], b0, acc[mi][0], 0, 0, 0);
      acc[mi][1] = __builtin_amdgcn_mfma_f32_16x16x32_bf16(a[mi], b1, acc[mi][1], 0, 0, 0);
    }
    __builtin_amdgcn_s_setprio(0);
    SCHEDB; BARRIER;

    // ---- P4: kh1, nh1 ----
    b0 = ds128(uB1 + boff + 2048);
    b1 = ds128(uB1 + boff + 3072);
    if (t + 2 < NT) STGA(c, 1, t + 2);
    SCHEDB; BARRIER; LGKM0; SCHEDB;
    __builtin_amdgcn_s_setprio(1);
#pragma unroll
    for (int mi = 0; mi < 8; ++mi) {
      acc[mi][2] = __builtin_amdgcn_mfma_f32_16x16x32_bf16(a[mi], b0, acc[mi][2], 0, 0, 0);
      acc[mi][3] = __builtin_amdgcn_mfma_f32_16x16x32_bf16(a[mi], b1, acc[mi][3], 0, 0, 0);
    }
    __builtin_amdgcn_s_setprio(0);
    SCHEDB;
    if (t < NT - 2) { WAITV(6); } else { WAITV(0); }
    BARRIER;
  }

  // epilogue; C/D layout: col = lane&15, row = (lane>>4)*4 + r  [m89/m91]
#pragma unroll
  for (int mi = 0; mi < 8; ++mi) {
#pragma unroll
    for (int ni = 0; ni < 4; ++ni) {
#pragma unroll
      for (int r = 0; r < 4; ++r) {
        const int row = m0 + wr * 128 + mi * 16 + (lane >> 4) * 4 + r;
        const int col = n0 + wc * 64 + ni * 16 + (lane & 15);
        float v = acc[mi][ni][r];
        if (MODE == 0) {
          const int id = col >> 10;        // 0=q 1=k 2=v (wave-uniform)
          const int cgl = col & 1023;
          const float* bp = (id == 0) ? bias0 : (id == 1 ? bias1 : bias2);
          v += bp[cgl];
          const int si = row & 63;
          if (id < 2) {
            const float pv = __shfl_xor(v, 1);
            const float2 cs = rope[(si << 9) + (cgl >> 1)];
            v = v * cs.x + ((lane & 1) ? pv * cs.y : -pv * cs.y);
          }
          const int bi = row >> 6;
          const int h = cgl >> 6, dh = cgl & 63;
          const size_t off = (((size_t)bi * NH + h) * SEQ + si) * HD + dh;
          const unsigned short bfv = f2bf(v);
          if (id == 0) qb[off] = bfv;
          else if (id == 1) kb[off] = bfv;
          else vb[off] = bfv;
        } else {
          outf[(size_t)row * DM + col] = v + bias0[col];
        }
      }
    }
  }
}

// ---------------- attention: one block per (b,h); S=64, HD=64 ---------------
__global__ __launch_bounds__(256, 4)
void attn_kernel(const unsigned short* __restrict__ qb,
                 const unsigned short* __restrict__ kbuf,
                 const unsigned short* __restrict__ vbuf,
                 unsigned short* __restrict__ vals) {
  __shared__ __align__(16) unsigned short sV[64 * 64];
  __shared__ __align__(16) unsigned short sP[64 * 64];
  const int bh = blockIdx.x;
  const int t = threadIdx.x, wave = t >> 6, lane = t & 63;
  const size_t base = (size_t)bh * 4096;

#pragma unroll
  for (int is = 0; is < 2; ++is) {
    const size_t go = base + is * 2048 + wave * 512 + (size_t)lane * 8;
    gload_lds16(vbuf + go, &sV[is * 2048 + wave * 512]);
  }

  const int rl = lane & 15, kq = (lane >> 4) * 8;
  bf16x8 aq[2];
#pragma unroll
  for (int kk = 0; kk < 2; ++kk)
    aq[kk] = *reinterpret_cast<const bf16x8*>(
        qb + base + (size_t)(wave * 16 + rl) * 64 + kk * 32 + kq);
  bf16x8 bk[4][2];
#pragma unroll
  for (int ni = 0; ni < 4; ++ni)
#pragma unroll
    for (int kk = 0; kk < 2; ++kk)
      bk[ni][kk] = *reinterpret_cast<const bf16x8*>(
          kbuf + base + (size_t)(ni * 16 + rl) * 64 + kk * 32 + kq);

  f32x4 sacc[4] = {};
#pragma unroll
  for (int kk = 0; kk < 2; ++kk)
#pragma unroll
    for (int ni = 0; ni < 4; ++ni)
      sacc[ni] = __builtin_amdgcn_mfma_f32_16x16x32_bf16(
          aq[kk], bk[ni][kk], sacc[ni], 0, 0, 0);
#pragma unroll
  for (int ni = 0; ni < 4; ++ni) sacc[ni] *= 0.125f;

#pragma unroll
  for (int r = 0; r < 4; ++r) {
    float mx = sacc[0][r];
#pragma unroll
    for (int ni = 1; ni < 4; ++ni) mx = fmaxf(mx, sacc[ni][r]);
#pragma unroll
    for (int off = 8; off; off >>= 1) mx = fmaxf(mx, __shfl_xor(mx, off));
    float e[4]; float sum = 0.f;
#pragma unroll
    for (int ni = 0; ni < 4; ++ni) { e[ni] = __expf(sacc[ni][r] - mx); sum += e[ni]; }
#pragma unroll
    for (int off = 8; off; off >>= 1) sum += __shfl_xor(sum, off);
    const float inv = 1.0f / sum;
    const int rowl = wave * 16 + (lane >> 4) * 4 + r;
#pragma unroll
    for (int ni = 0; ni < 4; ++ni)
      sP[rowl * 64 + ni * 16 + (lane & 15)] = f2bf(e[ni] * inv);
  }
  __syncthreads();

  f32x4 vacc[4] = {};
#pragma unroll
  for (int kk = 0; kk < 2; ++kk) {
    const int kb0 = kk * 32 + (lane >> 4) * 8;
    const bf16x8 ap = *reinterpret_cast<const bf16x8*>(
        &sP[(wave * 16 + (lane & 15)) * 64 + kb0]);
#pragma unroll
    for (int ni = 0; ni < 4; ++ni) {
      bf16x8 bvv;
      const int dh = ni * 16 + (lane & 15);
#pragma unroll
      for (int i = 0; i < 8; ++i)
        bvv[i] = __builtin_bit_cast(__bf16, sV[(kb0 + i) * 64 + dh]);
      vacc[ni] = __builtin_amdgcn_mfma_f32_16x16x32_bf16(ap, bvv, vacc[ni], 0, 0, 0);
    }
  }

  const int b = bh >> 4, h = bh & 15;
#pragma unroll
  for (int ni = 0; ni < 4; ++ni) {
#pragma unroll
    for (int r = 0; r < 4; ++r) {
      const int si = wave * 16 + (lane >> 4) * 4 + r;
      const int dh = ni * 16 + (lane & 15);
      vals[((size_t)b * SEQ + si) * DM + h * HD + dh] = f2bf(vacc[ni][r]);
    }
  }
}

// ---------------------------------------------------------------------------
extern "C" void kernel_launch(void* const* d_in, const int* in_sizes, int n_in,
                              void* d_out, int out_size, void* d_ws, size_t ws_size,
                              hipStream_t stream) {
  (void)in_sizes; (void)n_in; (void)out_size; (void)ws_size;
  const float* x  = (const float*)d_in[0];
  const float* Wq = (const float*)d_in[1];
  const float* bq = (const float*)d_in[2];
  const float* Wk = (const float*)d_in[3];
  const float* bk = (const float*)d_in[4];
  const float* Wv = (const float*)d_in[5];
  const float* bv = (const float*)d_in[6];
  const float* Wo = (const float*)d_in[7];
  const float* bo = (const float*)d_in[8];
  float* out = (float*)d_out;

  unsigned short* xb   = (unsigned short*)d_ws;
  unsigned short* wb   = xb + (size_t)MROWS * DM;
  unsigned short* qbuf = wb + 4ull * DM * DM;
  unsigned short* kbuf = qbuf + (size_t)MROWS * DM;
  unsigned short* vbuf = kbuf + (size_t)MROWS * DM;
  float2* rope = (float2*)(vbuf + (size_t)MROWS * DM);

  convert_all_kernel<<<2048, 256, 0, stream>>>(x, Wq, Wk, Wv, Wo, xb);
  rope_table_kernel<<<(SEQ * 512 + 255) / 256, 256, 0, stream>>>(rope);

  // QKV: M=32768, N=3072, K=1024 -> 128 x 12 = 1536 blocks
  gemm8p_kernel<0><<<(MROWS / 256) * (3 * DM / 256), 512, 0, stream>>>(
      xb, wb, bq, bk, bv, rope, qbuf, kbuf, vbuf, nullptr, 3 * DM / 256);

  attn_kernel<<<BATCH * NH, 256, 0, stream>>>(qbuf, kbuf, vbuf, xb);

  // O-proj: M=32768, N=1024, K=1024 -> 128 x 4 = 512 blocks
  gemm8p_kernel<1><<<(MROWS / 256) * (DM / 256), 512, 0, stream>>>(
      xb, wb + 3ull * DM * DM, bo, nullptr, nullptr, nullptr,
      nullptr, nullptr, nullptr, out, DM / 256);
}

// Round 10
// 471.073 us; speedup vs baseline: 1.0888x; 1.0888x over previous
//
#include <hip/hip_runtime.h>
#include <cstdint>
#include <cstddef>

#define DEVFN __device__ __forceinline__

typedef __attribute__((ext_vector_type(8))) __bf16 bf16x8;
typedef __attribute__((ext_vector_type(4))) float f32x4;
typedef __attribute__((ext_vector_type(16))) float f32x16;

static constexpr int DM = 1024;
static constexpr int NH = 16;
static constexpr int HD = 64;
static constexpr int BATCH = 512;
static constexpr int SEQ = 64;
static constexpr int MROWS = BATCH * SEQ;   // 32768
static constexpr int KDIM = DM;             // 1024

DEVFN unsigned short f2bf(float f) {
  unsigned u = __builtin_bit_cast(unsigned, f);
  u += 0x7fffu + ((u >> 16) & 1u);   // RNE
  return (unsigned short)(u >> 16);
}

DEVFN void gload_lds16(const void* g, void* l) {
  // async global->LDS, 16B per lane; LDS dest = wave-uniform base + lane*16B
  __builtin_amdgcn_global_load_lds(
      (__attribute__((address_space(1))) const void*)g,
      (__attribute__((address_space(3))) void*)l, 16, 0, 0);
}

// ------- one-shot fp32 -> bf16 convert of x + Wq|Wk|Wv|Wo into xb|wb -------
__global__ void convert_all_kernel(const float* __restrict__ x,
                                   const float* __restrict__ w0,
                                   const float* __restrict__ w1,
                                   const float* __restrict__ w2,
                                   const float* __restrict__ w3,
                                   unsigned short* __restrict__ dst) {
  const size_t NX = (size_t)MROWS * DM;          // 33.5M
  const size_t NTOT = NX + 4ull * DM * DM;       // +4M
  size_t i = ((size_t)blockIdx.x * blockDim.x + threadIdx.x) * 4;
  const size_t stride = (size_t)gridDim.x * blockDim.x * 4;
  for (; i < NTOT; i += stride) {
    const float* s;
    size_t off;
    if (i < NX) { s = x; off = i; }
    else {
      size_t j = i - NX;
      const int seg = (int)(j >> 20);
      off = j & ((1u << 20) - 1);
      s = (seg == 0) ? w0 : (seg == 1) ? w1 : (seg == 2) ? w2 : w3;
    }
    float4 f = *reinterpret_cast<const float4*>(s + off);
    ushort4 o;
    o.x = f2bf(f.x); o.y = f2bf(f.y); o.z = f2bf(f.z); o.w = f2bf(f.w);
    *reinterpret_cast<ushort4*>(dst + i) = o;
  }
}

// ---------------- RoPE cos/sin table: [SEQ][512] float2 ---------------------
__global__ void rope_table_kernel(float2* __restrict__ tab) {
  int idx = blockIdx.x * blockDim.x + threadIdx.x;
  if (idx >= SEQ * 512) return;
  int s = idx >> 9, i = idx & 511;
  float inv_freq = exp2f(-(float)i * (13.287712379549449f / 512.0f));
  float ang = (float)s * inv_freq;
  tab[idx] = make_float2(cosf(ang), sinf(ang));
}

// ==== 128x256 GEMM, BK=64, 8 waves, 32x32x16 MFMA, 2-phase (r3 schedule) ===
// C[M][N] = A[M][K] * B[N][K]^T (+epilogue)
// Same per-wave code as the round-3/8 666-TF kernel (64x64 out/wave, 16 MFMA
// + 6 ds_read_b128 per k-tile, XOR swizzle); only the block shape changes:
// 128x256 tile, 48 KB LDS -> 3 blocks x 8 waves = 24 waves/CU capacity
// (vs 13 at 128^2), nearly doubling the cross-wave overlap (m114) that the
// 2-phase structure relies on, and halving B re-fetch.
// MODE 0: QKV projection (N=3072): bias + RoPE on q,k; bf16 scatter to
//         q/k/v buffers [B][H][S][HD].
// MODE 1: O projection (N=1024): +bias, fp32 store.
template <int MODE>
__global__ __launch_bounds__(512, 2)
void gemm128x256_kernel(const unsigned short* __restrict__ A,
                        const unsigned short* __restrict__ Bw,
                        const float* __restrict__ bias0,
                        const float* __restrict__ bias1,
                        const float* __restrict__ bias2,
                        const float2* __restrict__ rope,
                        unsigned short* __restrict__ qb,
                        unsigned short* __restrict__ kb,
                        unsigned short* __restrict__ vb,
                        float* __restrict__ outf,
                        int Ntiles) {
  __shared__ __align__(16) unsigned short sA[128 * 64];   // 16 KB
  __shared__ __align__(16) unsigned short sB[256 * 64];   // 32 KB

  // T1: XCD-aware bijective swizzle (grid % 8 == 0 in both modes)
  const int cpx = gridDim.x >> 3;
  const int bid = (blockIdx.x & 7) * cpx + (blockIdx.x >> 3);
  const int bm = bid / Ntiles, bn = bid % Ntiles;
  const int m0 = bm * 128, n0 = bn * 256;

  const int tid = threadIdx.x;
  const int w = tid >> 6, lane = tid & 63;
  const int wr = w >> 2, wc = w & 3;   // 2M x 4N waves; 64x64 out per wave

  // staging: pre-swizzled global source, linear LDS dest (8 rows x 128B/instr)
  const int srow = tid >> 3;                       // 0..63
  const int scol = ((tid & 7) ^ (srow & 7)) * 8;   // swizzled k-slot (ushorts)
  const unsigned short* aB = A + ((size_t)m0 + srow) * KDIM + scol;
  const unsigned short* bB = Bw + ((size_t)n0 + srow) * KDIM + scol;

  f32x16 acc[2][2] = {};

  const int rA0 = wr * 64 + (lane & 31);
  const int rB0 = wc * 64 + (lane & 31);
  const int kq = (lane >> 5) * 8;                  // k sub-slot (ushorts)

  for (int t = 0; t < KDIM / 64; ++t) {
    const int k0 = t * 64;
#pragma unroll
    for (int p = 0; p < 2; ++p)
      gload_lds16(aB + ((size_t)p * 64) * KDIM + k0, &sA[p * 4096 + w * 512]);
#pragma unroll
    for (int p = 0; p < 4; ++p)
      gload_lds16(bB + ((size_t)p * 64) * KDIM + k0, &sB[p * 4096 + w * 512]);
    __syncthreads();   // drains vmcnt for global_load_lds
#pragma unroll
    for (int ks = 0; ks < 4; ++ks) {
      const int kb16 = ks * 16 + kq;
      bf16x8 a[2], b[2];
#pragma unroll
      for (int f = 0; f < 2; ++f) {
        const int r = rA0 + f * 32;
        a[f] = *reinterpret_cast<const bf16x8*>(&sA[r * 64 + (kb16 ^ ((r & 7) * 8))]);
      }
#pragma unroll
      for (int g = 0; g < 2; ++g) {
        const int r = rB0 + g * 32;
        b[g] = *reinterpret_cast<const bf16x8*>(&sB[r * 64 + (kb16 ^ ((r & 7) * 8))]);
      }
#pragma unroll
      for (int f = 0; f < 2; ++f)
#pragma unroll
        for (int g = 0; g < 2; ++g)
          acc[f][g] = __builtin_amdgcn_mfma_f32_32x32x16_bf16(
              a[f], b[g], acc[f][g], 0, 0, 0);
    }
    __syncthreads();
  }

  // epilogue; 32x32 C/D layout: col=lane&31, row=(reg&3)+8*(reg>>2)+4*(lane>>5)
#pragma unroll
  for (int f = 0; f < 2; ++f) {
#pragma unroll
    for (int g = 0; g < 2; ++g) {
#pragma unroll
      for (int reg = 0; reg < 16; ++reg) {
        const int rloc = (reg & 3) + 8 * (reg >> 2) + 4 * (lane >> 5);
        const int row = m0 + wr * 64 + f * 32 + rloc;
        const int col = n0 + wc * 64 + g * 32 + (lane & 31);
        float v = acc[f][g][reg];
        if (MODE == 0) {
          const int id = col >> 10;        // 0=q 1=k 2=v (block-uniform)
          const int c = col & 1023;
          const float* bp = (id == 0) ? bias0 : (id == 1 ? bias1 : bias2);
          v += bp[c];
          const int si = row & 63;
          if (id < 2) {
            // RoPE: col pair (2i,2i+1) lives in lanes (l, l^1)
            const float p = __shfl_xor(v, 1);
            const float2 cs = rope[(si << 9) + (c >> 1)];
            v = v * cs.x + ((lane & 1) ? p * cs.y : -p * cs.y);
          }
          const int bi = row >> 6;
          const int h = c >> 6, dh = c & 63;
          const size_t off = (((size_t)bi * NH + h) * SEQ + si) * HD + dh;
          const unsigned short bfv = f2bf(v);
          if (id == 0) qb[off] = bfv;
          else if (id == 1) kb[off] = bfv;
          else vb[off] = bfv;
        } else {
          outf[(size_t)row * DM + col] = v + bias0[col];
        }
      }
    }
  }
}

// ---------------- attention: one block per (b,h); S=64, HD=64 ---------------
// (round-3 version: Q,K,V all staged via coalesced global_load_lds)
__global__ __launch_bounds__(256, 4)
void attn_kernel(const unsigned short* __restrict__ qb,
                 const unsigned short* __restrict__ kbuf,
                 const unsigned short* __restrict__ vbuf,
                 unsigned short* __restrict__ vals) {
  __shared__ __align__(16) unsigned short sQ[64 * 64];
  __shared__ __align__(16) unsigned short sK[64 * 64];
  __shared__ __align__(16) unsigned short sV[64 * 64];
  __shared__ __align__(16) unsigned short sP[64 * 64];
  const int bh = blockIdx.x;              // b*NH + h
  const int t = threadIdx.x, wave = t >> 6, lane = t & 63;
  const size_t base = (size_t)bh * 4096;

#pragma unroll
  for (int is = 0; is < 2; ++is) {
    const size_t go = base + is * 2048 + wave * 512 + (size_t)lane * 8;
    const int lo = is * 2048 + wave * 512;
    gload_lds16(qb + go, &sQ[lo]);
    gload_lds16(kbuf + go, &sK[lo]);
    gload_lds16(vbuf + go, &sV[lo]);
  }
  __syncthreads();

  // S = Q K^T : wave owns 16 q-rows; 4 col-frags cover 64 keys
  f32x4 sacc[4] = {};
#pragma unroll
  for (int kk = 0; kk < 2; ++kk) {
    const int krow = kk * 32 + (lane >> 4) * 8;
    const bf16x8 aq = *reinterpret_cast<const bf16x8*>(
        &sQ[(wave * 16 + (lane & 15)) * 64 + krow]);
#pragma unroll
    for (int ni = 0; ni < 4; ++ni) {
      const bf16x8 bkf = *reinterpret_cast<const bf16x8*>(
          &sK[(ni * 16 + (lane & 15)) * 64 + krow]);
      sacc[ni] = __builtin_amdgcn_mfma_f32_16x16x32_bf16(aq, bkf, sacc[ni], 0, 0, 0);
    }
  }
#pragma unroll
  for (int ni = 0; ni < 4; ++ni) sacc[ni] *= 0.125f;   // 1/sqrt(64)

  // softmax across 64 cols: in-lane over 4 frags, then shfl-xor over 16 lanes
#pragma unroll
  for (int r = 0; r < 4; ++r) {
    float mx = sacc[0][r];
#pragma unroll
    for (int ni = 1; ni < 4; ++ni) mx = fmaxf(mx, sacc[ni][r]);
#pragma unroll
    for (int off = 8; off; off >>= 1) mx = fmaxf(mx, __shfl_xor(mx, off));
    float e[4]; float sum = 0.f;
#pragma unroll
    for (int ni = 0; ni < 4; ++ni) { e[ni] = __expf(sacc[ni][r] - mx); sum += e[ni]; }
#pragma unroll
    for (int off = 8; off; off >>= 1) sum += __shfl_xor(sum, off);
    const float inv = 1.0f / sum;
    const int rowl = wave * 16 + (lane >> 4) * 4 + r;
#pragma unroll
    for (int ni = 0; ni < 4; ++ni)
      sP[rowl * 64 + ni * 16 + (lane & 15)] = f2bf(e[ni] * inv);
  }
  __syncthreads();

  // vals = P V
  f32x4 vacc[4] = {};
#pragma unroll
  for (int kk = 0; kk < 2; ++kk) {
    const int kb0 = kk * 32 + (lane >> 4) * 8;
    const bf16x8 ap = *reinterpret_cast<const bf16x8*>(
        &sP[(wave * 16 + (lane & 15)) * 64 + kb0]);
#pragma unroll
    for (int ni = 0; ni < 4; ++ni) {
      bf16x8 bvv;
      const int dh = ni * 16 + (lane & 15);
#pragma unroll
      for (int i = 0; i < 8; ++i)
        bvv[i] = __builtin_bit_cast(__bf16, sV[(kb0 + i) * 64 + dh]);
      vacc[ni] = __builtin_amdgcn_mfma_f32_16x16x32_bf16(ap, bvv, vacc[ni], 0, 0, 0);
    }
  }

  // store vals bf16 into [MROWS][DM] layout (row=b*64+s, col=h*64+dh)
  const int b = bh >> 4, h = bh & 15;
#pragma unroll
  for (int ni = 0; ni < 4; ++ni) {
#pragma unroll
    for (int r = 0; r < 4; ++r) {
      const int si = wave * 16 + (lane >> 4) * 4 + r;
      const int dh = ni * 16 + (lane & 15);
      vals[((size_t)b * SEQ + si) * DM + h * HD + dh] = f2bf(vacc[ni][r]);
    }
  }
}

// ---------------------------------------------------------------------------
extern "C" void kernel_launch(void* const* d_in, const int* in_sizes, int n_in,
                              void* d_out, int out_size, void* d_ws, size_t ws_size,
                              hipStream_t stream) {
  (void)in_sizes; (void)n_in; (void)out_size; (void)ws_size;
  const float* x  = (const float*)d_in[0];
  const float* Wq = (const float*)d_in[1];
  const float* bq = (const float*)d_in[2];
  const float* Wk = (const float*)d_in[3];
  const float* bk = (const float*)d_in[4];
  const float* Wv = (const float*)d_in[5];
  const float* bv = (const float*)d_in[6];
  const float* Wo = (const float*)d_in[7];
  const float* bo = (const float*)d_in[8];
  float* out = (float*)d_out;

  // ws layout (bf16 buffers), total ~277 MB
  unsigned short* xb   = (unsigned short*)d_ws;            // x bf16; later reused for vals
  unsigned short* wb   = xb + (size_t)MROWS * DM;          // Wq|Wk|Wv|Wo bf16, [4096][1024]
  unsigned short* qbuf = wb + 4ull * DM * DM;              // [B][H][S][HD]
  unsigned short* kbuf = qbuf + (size_t)MROWS * DM;
  unsigned short* vbuf = kbuf + (size_t)MROWS * DM;
  float2* rope = (float2*)(vbuf + (size_t)MROWS * DM);     // [SEQ][512]

  convert_all_kernel<<<2048, 256, 0, stream>>>(x, Wq, Wk, Wv, Wo, xb);
  rope_table_kernel<<<(SEQ * 512 + 255) / 256, 256, 0, stream>>>(rope);

  // QKV projection: M=32768, N=3072, K=1024  (256 x 12 = 3072 blocks)
  gemm128x256_kernel<0><<<(MROWS / 128) * (3 * DM / 256), 512, 0, stream>>>(
      xb, wb, bq, bk, bv, rope, qbuf, kbuf, vbuf, nullptr, 3 * DM / 256);

  // attention per (b,h); writes vals (bf16) into xb buffer
  attn_kernel<<<BATCH * NH, 256, 0, stream>>>(qbuf, kbuf, vbuf, xb);

  // O projection: M=32768, N=1024, K=1024 -> fp32 out  (256 x 4 = 1024 blocks)
  gemm128x256_kernel<1><<<(MROWS / 128) * (DM / 256), 512, 0, stream>>>(
      xb, wb + 3ull * DM * DM, bo, nullptr, nullptr, nullptr,
      nullptr, nullptr, nullptr, out, DM / 256);
}